// Round 4
// baseline (3637.316 us; speedup 1.0000x reference)
//
#include <hip/hip_runtime.h>
#include <hip/hip_bf16.h>

// Sizes (fixed by the problem)
#define BATCH 128
#define SEQ   512
#define IND   512
#define FSD   128
#define HS    512
#define G4    (4 * HS)   // 2048
#define G2    (2 * HS)   // 1024

// rec partitioning
#define NG 8    // batch groups
#define GB 16   // batches per group
#define NS 32   // hidden slices
#define SJ 16   // hidden per slice

typedef short short8_t __attribute__((ext_vector_type(8)));
typedef float f32x4 __attribute__((ext_vector_type(4)));
typedef unsigned int uint4_t __attribute__((ext_vector_type(4)));

static __device__ __forceinline__ unsigned short f2bf(float f) {
    unsigned int u = __float_as_uint(f);
    unsigned int r = (u + 0x7fffu + ((u >> 16) & 1u)) >> 16;
    return (unsigned short)r;
}
static __device__ __forceinline__ float bf2f(unsigned short b) {
    return __uint_as_float(((unsigned int)b) << 16);
}
static __device__ __forceinline__ float sigmoidf_(float x) {
    return 1.0f / (1.0f + __expf(-x));
}
static __device__ __forceinline__ unsigned umin_(unsigned a, unsigned b) {
    return a < b ? a : b;
}

// ---------------------------------------------------------------------------
// Kernel 1: permute U_f [512][2048] f32 -> Up bf16 in MFMA B-fragment order.
// Up[(((s*4+g)*16+kt)*64+l)*8+i] = U_f[kt*32+(l>>4)*8+i][g*512+s*16+(l&15)]
// ---------------------------------------------------------------------------
__global__ __launch_bounds__(256)
void uconv_kernel(const float* __restrict__ Uf, unsigned short* __restrict__ Up) {
    int idx = blockIdx.x * 256 + threadIdx.x;   // 0 .. 2^20-1
    int i  = idx & 7;
    int l  = (idx >> 3) & 63;
    int kt = (idx >> 9) & 15;
    int g  = (idx >> 13) & 3;
    int s  = idx >> 15;
    int k  = kt * 32 + ((l >> 4) << 3) + i;
    int col = g * 512 + s * 16 + (l & 15);
    Up[idx] = f2bf(Uf[(size_t)k * G4 + col]);
}

// ---------------------------------------------------------------------------
// Kernel 1b: transpose+convert W_f [512][2048] f32 -> WfT [2048][512] bf16
// ---------------------------------------------------------------------------
__global__ __launch_bounds__(256)
void wtconv_kernel(const float* __restrict__ Wf, unsigned short* __restrict__ WfT) {
    __shared__ float tile[64][65];
    int k0 = blockIdx.x * 64;
    int n0 = blockIdx.y * 64;
    int tid = threadIdx.x;
    int r = tid >> 6, c = tid & 63;
    #pragma unroll
    for (int i = 0; i < 16; ++i)
        tile[r + 4 * i][c] = Wf[(size_t)(k0 + r + 4 * i) * G4 + n0 + c];
    __syncthreads();
    #pragma unroll
    for (int i = 0; i < 16; ++i)
        WfT[(size_t)(n0 + r + 4 * i) * IND + k0 + c] = f2bf(tile[c][r + 4 * i]);
}

// ---------------------------------------------------------------------------
// Kernel 2: lz = sigmoid(field@Wz[:, :512]+bz) * tanh(field@Wz[:, 512:]+bz)
// Output layout: lz[s][b][j] bf16
// ---------------------------------------------------------------------------
__global__ __launch_bounds__(256)
void lz_kernel(const float* __restrict__ field, const float* __restrict__ Wz,
               const float* __restrict__ biasz, unsigned short* __restrict__ lzOut) {
    __shared__ float fs[8][FSD];
    int b = blockIdx.x, s0 = blockIdx.y * 8;
    int tid = threadIdx.x;
    for (int u = tid; u < 8 * FSD; u += 256) {
        int r = u >> 7, k = u & 127;
        fs[r][k] = field[((size_t)b * SEQ + s0 + r) * FSD + k];
    }
    __syncthreads();
    #pragma unroll
    for (int jj = 0; jj < 2; ++jj) {
        int j = tid + jj * 256;
        float accl[8] = {0,0,0,0,0,0,0,0}, accz[8] = {0,0,0,0,0,0,0,0};
        for (int k = 0; k < FSD; ++k) {
            float wl = Wz[(size_t)k * G2 + j];
            float wz = Wz[(size_t)k * G2 + HS + j];
            #pragma unroll
            for (int r = 0; r < 8; ++r) {
                accl[r] += fs[r][k] * wl;
                accz[r] += fs[r][k] * wz;
            }
        }
        float bl = biasz[j], bz = biasz[HS + j];
        #pragma unroll
        for (int r = 0; r < 8; ++r) {
            float l = sigmoidf_(accl[r] + bl);
            float z = tanhf(accz[r] + bz);
            lzOut[(((size_t)(s0 + r)) * BATCH + b) * HS + j] = f2bf(l * z);
        }
    }
}

// ---------------------------------------------------------------------------
// Kernel 3: x_proj MFMA GEMM. A = word (f32, converted on the fly) with
// row = s*128+b; B = WfT bf16 [n][k]. C -> xp bf16 [s][b][4H] (+bias).
// Tile 128x128, BK=64, 4 waves (2x2 of 64x64), XOR-swizzled LDS.
// ---------------------------------------------------------------------------
#define XBM 128
#define XBN 128
#define XBK 64
__global__ __launch_bounds__(256)
void xmm_kernel(const float* __restrict__ word, const unsigned short* __restrict__ WfT,
                const float* __restrict__ bias, unsigned short* __restrict__ xp) {
    __shared__ unsigned short As[XBM * XBK];
    __shared__ unsigned short Bs[XBN * XBK];
    int tid = threadIdx.x;
    int l = tid & 63, w = tid >> 6;
    int wr = w >> 1, wc = w & 1;
    int row0 = blockIdx.x * XBM;
    int col0 = blockIdx.y * XBN;

    f32x4 acc[4][4];
    #pragma unroll
    for (int m = 0; m < 4; ++m)
        #pragma unroll
        for (int n = 0; n < 4; ++n)
            acc[m][n] = (f32x4){0.f, 0.f, 0.f, 0.f};

    for (int k0 = 0; k0 < IND; k0 += XBK) {
        float4 av[4][2];
        short8_t bv[4];
        #pragma unroll
        for (int i = 0; i < 4; ++i) {
            int c = tid + 256 * i;
            int ar = c >> 3, sub = c & 7;
            int grow = row0 + ar;
            int b_ = grow & 127, s_ = grow >> 7;
            const float* ap = word + ((size_t)b_ * SEQ + s_) * IND + k0 + sub * 8;
            av[i][0] = *(const float4*)ap;
            av[i][1] = *(const float4*)(ap + 4);
            bv[i] = *(const short8_t*)(WfT + (size_t)(col0 + ar) * IND + k0 + sub * 8);
        }
        __syncthreads();   // previous iter's compute done with LDS
        #pragma unroll
        for (int i = 0; i < 4; ++i) {
            int c = tid + 256 * i;
            int ar = c >> 3, sub = c & 7;
            int off = ar * 64 + ((sub ^ (ar & 7)) << 3);   // ushort units
            short8_t a8;
            a8[0] = (short)f2bf(av[i][0].x); a8[1] = (short)f2bf(av[i][0].y);
            a8[2] = (short)f2bf(av[i][0].z); a8[3] = (short)f2bf(av[i][0].w);
            a8[4] = (short)f2bf(av[i][1].x); a8[5] = (short)f2bf(av[i][1].y);
            a8[6] = (short)f2bf(av[i][1].z); a8[7] = (short)f2bf(av[i][1].w);
            *(short8_t*)&As[off] = a8;
            *(short8_t*)&Bs[off] = bv[i];
        }
        __syncthreads();
        #pragma unroll
        for (int kt = 0; kt < 2; ++kt) {
            short8_t af[4], bfr[4];
            #pragma unroll
            for (int m = 0; m < 4; ++m) {
                int r = wr * 64 + m * 16 + (l & 15);
                int sub = kt * 4 + (l >> 4);
                af[m] = *(const short8_t*)&As[r * 64 + ((sub ^ (r & 7)) << 3)];
                int cc = wc * 64 + m * 16 + (l & 15);
                bfr[m] = *(const short8_t*)&Bs[cc * 64 + ((sub ^ (cc & 7)) << 3)];
            }
            #pragma unroll
            for (int m = 0; m < 4; ++m)
                #pragma unroll
                for (int n = 0; n < 4; ++n)
                    acc[m][n] = __builtin_amdgcn_mfma_f32_16x16x32_bf16(
                        af[m], bfr[n], acc[m][n], 0, 0, 0);
        }
    }
    #pragma unroll
    for (int m = 0; m < 4; ++m) {
        int grow = row0 + wr * 64 + m * 16 + (l >> 4) * 4;
        #pragma unroll
        for (int n = 0; n < 4; ++n) {
            int gcol = col0 + wc * 64 + n * 16 + (l & 15);
            float bsv = bias[gcol];
            #pragma unroll
            for (int r = 0; r < 4; ++r)
                xp[(size_t)(grow + r) * G4 + gcol] = f2bf(acc[m][n][r] + bsv);
        }
    }
}

// ---------------------------------------------------------------------------
// Kernel 4: recurrence with TAGGED-DATA sync. h element = u32
// (bf16 | (t+1)<<16) in hbuf (u32, A-fragment order, double-buffered by t&1).
// Consumers poll the data itself with coherent (sc0 sc1) loads — no counter,
// no producer-side waits, single IC round trip per step.
// ---------------------------------------------------------------------------
__global__ __launch_bounds__(256, 1)
void rec4_kernel(const unsigned short* __restrict__ xp,
                 const unsigned short* __restrict__ lz,
                 const unsigned short* __restrict__ Up,
                 float* __restrict__ out,
                 unsigned int* __restrict__ hbuf) {
    const size_t HSEQ = (size_t)BATCH * SEQ * HS;
    const int HBG = GB * HS;   // 8192 u32 per (slot, group)

    int bid = blockIdx.x;
    int g = bid & 7;
    int s = bid >> 3;
    int tid = threadIdx.x;
    int w = tid >> 6;
    int l = tid & 63;

    // B preload: 16 k-tile fragments of U for (slice s, gate w)
    short8_t Bf[16];
    const short8_t* upw = (const short8_t*)(Up + ((size_t)(s * 4 + w) * 16) * 512);
    #pragma unroll
    for (int kt = 0; kt < 16; ++kt) Bf[kt] = upw[kt * 64 + l];

    __shared__ float gbuf[4][16][17];

    int eb = tid >> 4;
    int ej = tid & 15;
    int jg = s * SJ + ej;
    int bg = g * GB + eb;
    // u32 element index in A-fragment order for h[b=eb][j=jg]
    int widx = (((jg >> 5) * 64 + eb + (((jg >> 3) & 3) << 4)) << 3) + (jg & 7);

    float c = 0.f, h_last = 0.f;

    for (int t = 0; t < SEQ; ++t) {
        // prefetch gate inputs (independent of h)
        size_t xb = ((size_t)t * BATCH + bg) * G4;
        float pgi = bf2f(xp[xb + jg]);
        float pgf = bf2f(xp[xb + HS + jg]);
        float pgg = bf2f(xp[xb + 2 * HS + jg]);
        float pgo = bf2f(xp[xb + 3 * HS + jg]);
        float plz = bf2f(lz[((size_t)t * BATCH + bg) * HS + jg]);

        f32x4 acc0 = {0.f, 0.f, 0.f, 0.f};
        f32x4 acc1 = {0.f, 0.f, 0.f, 0.f};
        if (t > 0) {
            const unsigned int* ha =
                hbuf + (size_t)(((t - 1) & 1) * NG + g) * HBG + l * 8;
            unsigned expect = (unsigned)t;    // tag of h_{t-1}
            uint4_t ra[16], rb[16];
            int spins = 0;
            for (;;) {
                #pragma unroll
                for (int kt = 0; kt < 16; ++kt) {
                    const unsigned int* p = ha + kt * 512;
                    asm volatile(
                        "global_load_dwordx4 %0, %2, off sc0 sc1\n\t"
                        "global_load_dwordx4 %1, %2, off offset:16 sc0 sc1"
                        : "=v"(ra[kt]), "=v"(rb[kt]) : "v"(p));
                }
                asm volatile("s_waitcnt vmcnt(0)" ::: "memory");
                unsigned mn = 0xffffffffu;
                #pragma unroll
                for (int kt = 0; kt < 16; ++kt) {
                    uint4_t x = ra[kt], y = rb[kt];
                    unsigned m0 = umin_(umin_(x.x, x.y), umin_(x.z, x.w));
                    unsigned m1 = umin_(umin_(y.x, y.y), umin_(y.z, y.w));
                    mn = umin_(mn, umin_(m0, m1));
                }
                if ((mn >> 16) == expect || ++spins > (1 << 16)) break;
            }
            // strip tags -> bf16 A fragments, MFMA
            #pragma unroll
            for (int kt = 0; kt < 16; ++kt) {
                union { unsigned int u[4]; short8_t v; } A;
                A.u[0] = __builtin_amdgcn_perm(ra[kt].y, ra[kt].x, 0x05040100u);
                A.u[1] = __builtin_amdgcn_perm(ra[kt].w, ra[kt].z, 0x05040100u);
                A.u[2] = __builtin_amdgcn_perm(rb[kt].y, rb[kt].x, 0x05040100u);
                A.u[3] = __builtin_amdgcn_perm(rb[kt].w, rb[kt].z, 0x05040100u);
                if (kt & 1)
                    acc1 = __builtin_amdgcn_mfma_f32_16x16x32_bf16(A.v, Bf[kt], acc1, 0, 0, 0);
                else
                    acc0 = __builtin_amdgcn_mfma_f32_16x16x32_bf16(A.v, Bf[kt], acc0, 0, 0, 0);
            }
            acc0 += acc1;
        }
        // stash gate tile: D layout col=lane&15, row=(lane>>4)*4+reg
        #pragma unroll
        for (int r = 0; r < 4; ++r)
            gbuf[w][(l >> 4) * 4 + r][l & 15] = acc0[r];
        __syncthreads();

        // epilogue: thread (eb, ej)
        float gi = gbuf[0][eb][ej] + pgi;
        float gf = gbuf[1][eb][ej] + pgf;
        float gg = gbuf[2][eb][ej] + pgg;
        float go = gbuf[3][eb][ej] + pgo;
        float i_ = sigmoidf_(gi);
        float f_ = sigmoidf_(gf + 1.0f);
        float g_ = tanhf(gg);
        float o_ = sigmoidf_(go);
        c = f_ * c + i_ * g_ + plz;
        float h = o_ * tanhf(c);
        h_last = h;
        out[((size_t)bg * SEQ + t) * HS + jg] = h;

        // tagged h store (write-through to coherence point); no wait needed
        unsigned int tagval = (unsigned int)f2bf(h) | ((unsigned int)(t + 1) << 16);
        unsigned int* hb = hbuf + (size_t)((t & 1) * NG + g) * HBG;
        __hip_atomic_store(&hb[widx], tagval, __ATOMIC_RELAXED,
                           __HIP_MEMORY_SCOPE_AGENT);
        // NOTE: no trailing __syncthreads — next step's poll transitively
        // proves all waves' gbuf reads of this step retired (data dependency
        // h-store <- gbuf reads; poll covers own block's slice elements).
    }

    out[HSEQ + (size_t)bg * HS + jg] = h_last;
    out[HSEQ + (size_t)BATCH * HS + (size_t)bg * HS + jg] = c;
}

// ---------------------------------------------------------------------------
extern "C" void kernel_launch(void* const* d_in, const int* in_sizes, int n_in,
                              void* d_out, int out_size, void* d_ws, size_t ws_size,
                              hipStream_t stream) {
    const float* word   = (const float*)d_in[0];
    const float* field  = (const float*)d_in[1];
    const float* Wf     = (const float*)d_in[2];
    const float* Wz     = (const float*)d_in[3];
    const float* Uf     = (const float*)d_in[4];
    const float* bias_f = (const float*)d_in[5];
    const float* biasz  = (const float*)d_in[6];
    float* out = (float*)d_out;

    // Workspace:
    //   xp  : bf16 [S][B][4H] = 268,435,456
    //   lz  : bf16 [S][B][H]  =  67,108,864
    //   Up  : bf16 frag-order =   2,097,152
    //   WfT : bf16 [N][K]     =   2,097,152
    //   hbuf: u32  2x8x8192   =     524,288
    char* p = (char*)d_ws;
    unsigned short* xp  = (unsigned short*)p;  p += (size_t)SEQ * BATCH * G4 * 2;
    unsigned short* lzb = (unsigned short*)p;  p += (size_t)SEQ * BATCH * HS * 2;
    unsigned short* Up  = (unsigned short*)p;  p += (size_t)IND * G4 * 2;
    unsigned short* WfT = (unsigned short*)p;  p += (size_t)G4 * IND * 2;
    unsigned int*   hbuf= (unsigned int*)p;    p += (size_t)2 * NG * GB * HS * 4;

    // clear tags (harness does NOT re-poison ws between graph replays)
    hipMemsetAsync(hbuf, 0, (size_t)2 * NG * GB * HS * 4, stream);

    uconv_kernel<<<(IND * G4) / 256, 256, 0, stream>>>(Uf, Up);

    dim3 gt(IND / 64, G4 / 64);
    wtconv_kernel<<<gt, 256, 0, stream>>>(Wf, WfT);

    dim3 gl(BATCH, SEQ / 8);
    lz_kernel<<<gl, 256, 0, stream>>>(field, Wz, biasz, lzb);

    dim3 gx((SEQ * BATCH) / XBM, G4 / XBN);
    xmm_kernel<<<gx, 256, 0, stream>>>(word, WfT, bias_f, xp);

    rec4_kernel<<<NG * NS, 256, 0, stream>>>(xp, lzb, Up, out, hbuf);
}

// Round 5
// 2788.640 us; speedup vs baseline: 1.3043x; 1.3043x over previous
//
#include <hip/hip_runtime.h>
#include <hip/hip_bf16.h>

// Sizes (fixed by the problem)
#define BATCH 128
#define SEQ   512
#define IND   512
#define FSD   128
#define HS    512
#define G4    (4 * HS)   // 2048
#define G2    (2 * HS)   // 1024

// rec partitioning: 8 groups x 16 blocks; block = 2 col-slices (32 j), 4 gates
#define NG 8    // batch groups
#define GB 16   // batches per group
#define NB 16   // blocks per group
#define SJ 32   // hidden columns per block (2 x 16-slices)

typedef short short8_t __attribute__((ext_vector_type(8)));
typedef float f32x4 __attribute__((ext_vector_type(4)));

static __device__ __forceinline__ unsigned short f2bf(float f) {
    unsigned int u = __float_as_uint(f);
    unsigned int r = (u + 0x7fffu + ((u >> 16) & 1u)) >> 16;
    return (unsigned short)r;
}
static __device__ __forceinline__ float bf2f(unsigned short b) {
    return __uint_as_float(((unsigned int)b) << 16);
}
static __device__ __forceinline__ float sigmoidf_(float x) {
    return 1.0f / (1.0f + __expf(-x));
}

// ---------------------------------------------------------------------------
// Kernel 1: permute U_f [512][2048] f32 -> Up bf16 in MFMA B-fragment order.
// Up[(((s*4+g)*16+kt)*64+l)*8+i] = U_f[kt*32+(l>>4)*8+i][g*512+s*16+(l&15)]
// (s = 16-col slice index 0..31, g = gate)
// ---------------------------------------------------------------------------
__global__ __launch_bounds__(256)
void uconv_kernel(const float* __restrict__ Uf, unsigned short* __restrict__ Up) {
    int idx = blockIdx.x * 256 + threadIdx.x;   // 0 .. 2^20-1
    int i  = idx & 7;
    int l  = (idx >> 3) & 63;
    int kt = (idx >> 9) & 15;
    int g  = (idx >> 13) & 3;
    int s  = idx >> 15;
    int k  = kt * 32 + ((l >> 4) << 3) + i;
    int col = g * 512 + s * 16 + (l & 15);
    Up[idx] = f2bf(Uf[(size_t)k * G4 + col]);
}

// ---------------------------------------------------------------------------
// Kernel 1b: transpose+convert W_f [512][2048] f32 -> WfT [2048][512] bf16
// ---------------------------------------------------------------------------
__global__ __launch_bounds__(256)
void wtconv_kernel(const float* __restrict__ Wf, unsigned short* __restrict__ WfT) {
    __shared__ float tile[64][65];
    int k0 = blockIdx.x * 64;
    int n0 = blockIdx.y * 64;
    int tid = threadIdx.x;
    int r = tid >> 6, c = tid & 63;
    #pragma unroll
    for (int i = 0; i < 16; ++i)
        tile[r + 4 * i][c] = Wf[(size_t)(k0 + r + 4 * i) * G4 + n0 + c];
    __syncthreads();
    #pragma unroll
    for (int i = 0; i < 16; ++i)
        WfT[(size_t)(n0 + r + 4 * i) * IND + k0 + c] = f2bf(tile[c][r + 4 * i]);
}

// ---------------------------------------------------------------------------
// Kernel 2: lz = sigmoid(field@Wz[:, :512]+bz) * tanh(field@Wz[:, 512:]+bz)
// Output layout: lz[s][b][j] bf16
// ---------------------------------------------------------------------------
__global__ __launch_bounds__(256)
void lz_kernel(const float* __restrict__ field, const float* __restrict__ Wz,
               const float* __restrict__ biasz, unsigned short* __restrict__ lzOut) {
    __shared__ float fs[8][FSD];
    int b = blockIdx.x, s0 = blockIdx.y * 8;
    int tid = threadIdx.x;
    for (int u = tid; u < 8 * FSD; u += 256) {
        int r = u >> 7, k = u & 127;
        fs[r][k] = field[((size_t)b * SEQ + s0 + r) * FSD + k];
    }
    __syncthreads();
    #pragma unroll
    for (int jj = 0; jj < 2; ++jj) {
        int j = tid + jj * 256;
        float accl[8] = {0,0,0,0,0,0,0,0}, accz[8] = {0,0,0,0,0,0,0,0};
        for (int k = 0; k < FSD; ++k) {
            float wl = Wz[(size_t)k * G2 + j];
            float wz = Wz[(size_t)k * G2 + HS + j];
            #pragma unroll
            for (int r = 0; r < 8; ++r) {
                accl[r] += fs[r][k] * wl;
                accz[r] += fs[r][k] * wz;
            }
        }
        float bl = biasz[j], bz = biasz[HS + j];
        #pragma unroll
        for (int r = 0; r < 8; ++r) {
            float l = sigmoidf_(accl[r] + bl);
            float z = tanhf(accz[r] + bz);
            lzOut[(((size_t)(s0 + r)) * BATCH + b) * HS + j] = f2bf(l * z);
        }
    }
}

// ---------------------------------------------------------------------------
// Kernel 3: x_proj MFMA GEMM. A = word (f32, converted on the fly) with
// row = s*128+b; B = WfT bf16 [n][k]. C -> xp bf16 [s][b][4H] (+bias).
// Tile 128x128, BK=64, 4 waves (2x2 of 64x64), XOR-swizzled LDS.
// ---------------------------------------------------------------------------
#define XBM 128
#define XBN 128
#define XBK 64
__global__ __launch_bounds__(256)
void xmm_kernel(const float* __restrict__ word, const unsigned short* __restrict__ WfT,
                const float* __restrict__ bias, unsigned short* __restrict__ xp) {
    __shared__ unsigned short As[XBM * XBK];
    __shared__ unsigned short Bs[XBN * XBK];
    int tid = threadIdx.x;
    int l = tid & 63, w = tid >> 6;
    int wr = w >> 1, wc = w & 1;
    int row0 = blockIdx.x * XBM;
    int col0 = blockIdx.y * XBN;

    f32x4 acc[4][4];
    #pragma unroll
    for (int m = 0; m < 4; ++m)
        #pragma unroll
        for (int n = 0; n < 4; ++n)
            acc[m][n] = (f32x4){0.f, 0.f, 0.f, 0.f};

    for (int k0 = 0; k0 < IND; k0 += XBK) {
        float4 av[4][2];
        short8_t bv[4];
        #pragma unroll
        for (int i = 0; i < 4; ++i) {
            int c = tid + 256 * i;
            int ar = c >> 3, sub = c & 7;
            int grow = row0 + ar;
            int b_ = grow & 127, s_ = grow >> 7;
            const float* ap = word + ((size_t)b_ * SEQ + s_) * IND + k0 + sub * 8;
            av[i][0] = *(const float4*)ap;
            av[i][1] = *(const float4*)(ap + 4);
            bv[i] = *(const short8_t*)(WfT + (size_t)(col0 + ar) * IND + k0 + sub * 8);
        }
        __syncthreads();   // previous iter's compute done with LDS
        #pragma unroll
        for (int i = 0; i < 4; ++i) {
            int c = tid + 256 * i;
            int ar = c >> 3, sub = c & 7;
            int off = ar * 64 + ((sub ^ (ar & 7)) << 3);   // ushort units
            short8_t a8;
            a8[0] = (short)f2bf(av[i][0].x); a8[1] = (short)f2bf(av[i][0].y);
            a8[2] = (short)f2bf(av[i][0].z); a8[3] = (short)f2bf(av[i][0].w);
            a8[4] = (short)f2bf(av[i][1].x); a8[5] = (short)f2bf(av[i][1].y);
            a8[6] = (short)f2bf(av[i][1].z); a8[7] = (short)f2bf(av[i][1].w);
            *(short8_t*)&As[off] = a8;
            *(short8_t*)&Bs[off] = bv[i];
        }
        __syncthreads();
        #pragma unroll
        for (int kt = 0; kt < 2; ++kt) {
            short8_t af[4], bfr[4];
            #pragma unroll
            for (int m = 0; m < 4; ++m) {
                int r = wr * 64 + m * 16 + (l & 15);
                int sub = kt * 4 + (l >> 4);
                af[m] = *(const short8_t*)&As[r * 64 + ((sub ^ (r & 7)) << 3)];
                int cc = wc * 64 + m * 16 + (l & 15);
                bfr[m] = *(const short8_t*)&Bs[cc * 64 + ((sub ^ (cc & 7)) << 3)];
            }
            #pragma unroll
            for (int m = 0; m < 4; ++m)
                #pragma unroll
                for (int n = 0; n < 4; ++n)
                    acc[m][n] = __builtin_amdgcn_mfma_f32_16x16x32_bf16(
                        af[m], bfr[n], acc[m][n], 0, 0, 0);
        }
    }
    #pragma unroll
    for (int m = 0; m < 4; ++m) {
        int grow = row0 + wr * 64 + m * 16 + (l >> 4) * 4;
        #pragma unroll
        for (int n = 0; n < 4; ++n) {
            int gcol = col0 + wc * 64 + n * 16 + (l & 15);
            float bsv = bias[gcol];
            #pragma unroll
            for (int r = 0; r < 4; ++r)
                xp[(size_t)(grow + r) * G4 + gcol] = f2bf(acc[m][n][r] + bsv);
        }
    }
}

// ---------------------------------------------------------------------------
// Kernel 4: recurrence, flag-per-block sync.
// Grid 128 blocks x 256 threads: g = bid&7 (group of 16 batches),
// s = bid>>3 in [0,16) covers cols [s*32, s*32+32) of all 4 gates.
// Wave w = gate; each wave: 2 B-fragment sets in regs, 2 output tiles.
// Protocol per step: h-stores (sc0sc1) -> barrier (vmcnt drain) -> flag store;
// consumers poll the 16 flags (one cacheline), then bulk-load A fragments.
// ---------------------------------------------------------------------------
__global__ __launch_bounds__(256, 1)
void rec5_kernel(const unsigned short* __restrict__ xp,
                 const unsigned short* __restrict__ lz,
                 const unsigned short* __restrict__ Up,
                 float* __restrict__ out,
                 unsigned short* __restrict__ hbuf,
                 unsigned int* __restrict__ flags) {
    const size_t HSEQ = (size_t)BATCH * SEQ * HS;
    const int HBG = GB * HS;   // 8192 ushorts per (slot, group)

    int bid = blockIdx.x;
    int g = bid & 7;
    int s = bid >> 3;          // 0..15
    int tid = threadIdx.x;
    int w = tid >> 6;          // gate
    int l = tid & 63;

    // B preload: 2 slice-sets x 16 k-tiles for (slices 2s, 2s+1; gate w)
    short8_t BfA[16], BfB[16];
    const short8_t* upwA = (const short8_t*)(Up + ((size_t)((2 * s) * 4 + w) * 16) * 512);
    const short8_t* upwB = (const short8_t*)(Up + ((size_t)((2 * s + 1) * 4 + w) * 16) * 512);
    #pragma unroll
    for (int kt = 0; kt < 16; ++kt) {
        BfA[kt] = upwA[kt * 64 + l];
        BfB[kt] = upwB[kt * 64 + l];
    }

    __shared__ float gbuf[4][16][34];   // 2-way (free) bank pattern

    // epilogue ownership: thread -> (eb0, ej) and (eb0+8, ej)
    int ej = tid & 31;            // col within block's 32
    int eb0 = tid >> 5;           // 0..7
    int jg = s * SJ + ej;         // global hidden col
    int bg0 = g * GB + eb0;
    int bg1 = bg0 + 8;
    // hbuf ushort index for h[b][j] in A-fragment order
    //   widx(b,j) = ((j>>5)*64 + b + (((j>>3)&3)<<4))*8 + (j&7)
    int w0 = (((jg >> 5) * 64 + eb0 + (((jg >> 3) & 3) << 4)) << 3) + (jg & 7);
    int w1 = w0 + (8 << 3);       // b+8 -> +8 lanes -> +64 ushorts

    unsigned int* fl = flags + (size_t)g * SEQ * NB;

    float c0 = 0.f, c1 = 0.f, h0l = 0.f, h1l = 0.f;

    for (int t = 0; t < SEQ; ++t) {
        // prefetch gate inputs for this step (independent of h)
        size_t xb0 = ((size_t)t * BATCH + bg0) * G4;
        size_t xb1 = ((size_t)t * BATCH + bg1) * G4;
        float pgi0 = bf2f(xp[xb0 + jg]);
        float pgf0 = bf2f(xp[xb0 + HS + jg]);
        float pgg0 = bf2f(xp[xb0 + 2 * HS + jg]);
        float pgo0 = bf2f(xp[xb0 + 3 * HS + jg]);
        float pgi1 = bf2f(xp[xb1 + jg]);
        float pgf1 = bf2f(xp[xb1 + HS + jg]);
        float pgg1 = bf2f(xp[xb1 + 2 * HS + jg]);
        float pgo1 = bf2f(xp[xb1 + 3 * HS + jg]);
        float plz0 = bf2f(lz[((size_t)t * BATCH + bg0) * HS + jg]);
        float plz1 = bf2f(lz[((size_t)t * BATCH + bg1) * HS + jg]);

        f32x4 aA0 = {0.f,0.f,0.f,0.f}, aA1 = {0.f,0.f,0.f,0.f};
        f32x4 aB0 = {0.f,0.f,0.f,0.f}, aB1 = {0.f,0.f,0.f,0.f};
        if (t > 0) {
            // poll the 16 producer flags of step t-1 (all waves, 1 line)
            const unsigned int* fp = fl + (size_t)(t - 1) * NB + (l & 15);
            int spins = 0;
            unsigned v;
            do {
                v = __hip_atomic_load(fp, __ATOMIC_RELAXED,
                                      __HIP_MEMORY_SCOPE_AGENT);
                if (++spins > (1 << 20)) break;
            } while (!__all(v == (unsigned)t));

            const unsigned long long* ha64 = (const unsigned long long*)
                (hbuf + (size_t)(((t - 1) & 1) * NG + g) * HBG);
            #pragma unroll
            for (int kt = 0; kt < 16; ++kt) {
                union { unsigned long long u[2]; short8_t v8; } A;
                int i0 = (kt * 64 + l) * 2;
                A.u[0] = __hip_atomic_load(&ha64[i0], __ATOMIC_RELAXED,
                                           __HIP_MEMORY_SCOPE_AGENT);
                A.u[1] = __hip_atomic_load(&ha64[i0 + 1], __ATOMIC_RELAXED,
                                           __HIP_MEMORY_SCOPE_AGENT);
                if (kt & 1) {
                    aA1 = __builtin_amdgcn_mfma_f32_16x16x32_bf16(A.v8, BfA[kt], aA1, 0, 0, 0);
                    aB1 = __builtin_amdgcn_mfma_f32_16x16x32_bf16(A.v8, BfB[kt], aB1, 0, 0, 0);
                } else {
                    aA0 = __builtin_amdgcn_mfma_f32_16x16x32_bf16(A.v8, BfA[kt], aA0, 0, 0, 0);
                    aB0 = __builtin_amdgcn_mfma_f32_16x16x32_bf16(A.v8, BfB[kt], aB0, 0, 0, 0);
                }
            }
            aA0 += aA1;
            aB0 += aB1;
        }
        // D layout: row(batch) = (l>>4)*4+r, col(j) = l&15
        #pragma unroll
        for (int r = 0; r < 4; ++r) {
            gbuf[w][(l >> 4) * 4 + r][l & 15] = aA0[r];
            gbuf[w][(l >> 4) * 4 + r][16 + (l & 15)] = aB0[r];
        }
        __syncthreads();

        // epilogue: 2 (b,j) pairs per thread
        float gi0 = gbuf[0][eb0][ej] + pgi0;
        float gf0 = gbuf[1][eb0][ej] + pgf0;
        float gg0 = gbuf[2][eb0][ej] + pgg0;
        float go0 = gbuf[3][eb0][ej] + pgo0;
        float gi1 = gbuf[0][eb0 + 8][ej] + pgi1;
        float gf1 = gbuf[1][eb0 + 8][ej] + pgf1;
        float gg1 = gbuf[2][eb0 + 8][ej] + pgg1;
        float go1 = gbuf[3][eb0 + 8][ej] + pgo1;
        float i0 = sigmoidf_(gi0), f0 = sigmoidf_(gf0 + 1.0f);
        float q0 = tanhf(gg0),     o0 = sigmoidf_(go0);
        float i1 = sigmoidf_(gi1), f1 = sigmoidf_(gf1 + 1.0f);
        float q1 = tanhf(gg1),     o1 = sigmoidf_(go1);
        c0 = f0 * c0 + i0 * q0 + plz0;
        c1 = f1 * c1 + i1 * q1 + plz1;
        float h0 = o0 * tanhf(c0);
        float h1 = o1 * tanhf(c1);
        h0l = h0; h1l = h1;

        // h exchange: pack u32 pairs, coherent stores (write-through)
        unsigned short hv0 = f2bf(h0), hv1 = f2bf(h1);
        unsigned p0 = (unsigned)(unsigned short)__shfl_down((int)hv0, 1);
        unsigned p1 = (unsigned)(unsigned short)__shfl_down((int)hv1, 1);
        if ((ej & 1) == 0) {
            unsigned int* hb32 = (unsigned int*)
                (hbuf + (size_t)((t & 1) * NG + g) * HBG);
            __hip_atomic_store(&hb32[w0 >> 1], (unsigned)hv0 | (p0 << 16),
                               __ATOMIC_RELAXED, __HIP_MEMORY_SCOPE_AGENT);
            __hip_atomic_store(&hb32[w1 >> 1], (unsigned)hv1 | (p1 << 16),
                               __ATOMIC_RELAXED, __HIP_MEMORY_SCOPE_AGENT);
        }
        asm volatile("s_waitcnt vmcnt(0)" ::: "memory");
        __syncthreads();   // all waves' h stores drained; gbuf reads done
        if (tid == 0)
            __hip_atomic_store(&fl[(size_t)t * NB + s], (unsigned)(t + 1),
                               __ATOMIC_RELAXED, __HIP_MEMORY_SCOPE_AGENT);

        // hidden-seq output AFTER flag publication (off the critical path)
        out[((size_t)bg0 * SEQ + t) * HS + jg] = h0;
        out[((size_t)bg1 * SEQ + t) * HS + jg] = h1;
    }

    // finals: h_T then c_T
    out[HSEQ + (size_t)bg0 * HS + jg] = h0l;
    out[HSEQ + (size_t)bg1 * HS + jg] = h1l;
    out[HSEQ + (size_t)BATCH * HS + (size_t)bg0 * HS + jg] = c0;
    out[HSEQ + (size_t)BATCH * HS + (size_t)bg1 * HS + jg] = c1;
}

// ---------------------------------------------------------------------------
extern "C" void kernel_launch(void* const* d_in, const int* in_sizes, int n_in,
                              void* d_out, int out_size, void* d_ws, size_t ws_size,
                              hipStream_t stream) {
    const float* word   = (const float*)d_in[0];
    const float* field  = (const float*)d_in[1];
    const float* Wf     = (const float*)d_in[2];
    const float* Wz     = (const float*)d_in[3];
    const float* Uf     = (const float*)d_in[4];
    const float* bias_f = (const float*)d_in[5];
    const float* biasz  = (const float*)d_in[6];
    float* out = (float*)d_out;

    // Workspace:
    //   xp   : bf16 [S][B][4H] = 268,435,456
    //   lz   : bf16 [S][B][H]  =  67,108,864
    //   Up   : bf16 frag-order =   2,097,152
    //   WfT  : bf16 [N][K]     =   2,097,152
    //   hbuf : bf16 2x8x8192   =     262,144
    //   flags: u32 8x512x16    =     262,144
    char* p = (char*)d_ws;
    unsigned short* xp   = (unsigned short*)p;  p += (size_t)SEQ * BATCH * G4 * 2;
    unsigned short* lzb  = (unsigned short*)p;  p += (size_t)SEQ * BATCH * HS * 2;
    unsigned short* Up   = (unsigned short*)p;  p += (size_t)IND * G4 * 2;
    unsigned short* WfT  = (unsigned short*)p;  p += (size_t)G4 * IND * 2;
    unsigned short* hbuf = (unsigned short*)p;  p += (size_t)2 * NG * GB * HS * 2;
    unsigned int*   flags= (unsigned int*)p;    p += (size_t)NG * SEQ * NB * 4;

    // clear flags (harness does NOT re-poison ws between graph replays)
    hipMemsetAsync(flags, 0, (size_t)NG * SEQ * NB * 4, stream);

    uconv_kernel<<<(IND * G4) / 256, 256, 0, stream>>>(Uf, Up);

    dim3 gt(IND / 64, G4 / 64);
    wtconv_kernel<<<gt, 256, 0, stream>>>(Wf, WfT);

    dim3 gl(BATCH, SEQ / 8);
    lz_kernel<<<gl, 256, 0, stream>>>(field, Wz, biasz, lzb);

    dim3 gx((SEQ * BATCH) / XBM, G4 / XBN);
    xmm_kernel<<<gx, 256, 0, stream>>>(word, WfT, bias_f, xp);

    rec5_kernel<<<NG * NB, 256, 0, stream>>>(xp, lzb, Up, out, hbuf, flags);
}

// Round 7
// 2389.328 us; speedup vs baseline: 1.5223x; 1.1671x over previous
//
#include <hip/hip_runtime.h>
#include <hip/hip_bf16.h>

// Sizes (fixed by the problem)
#define BATCH 128
#define SEQ   512
#define IND   512
#define FSD   128
#define HS    512
#define G4    (4 * HS)   // 2048
#define G2    (2 * HS)   // 1024

// rec partitioning: 8 groups x 32 blocks; block = one 16-col slice, 4 gates
#define NG 8    // batch groups
#define GB 16   // batches per group
#define NS 32   // hidden slices (blocks per group)
#define SJ 16   // hidden per slice

typedef short short8_t __attribute__((ext_vector_type(8)));
typedef float f32x4 __attribute__((ext_vector_type(4)));

static __device__ __forceinline__ unsigned short f2bf(float f) {
    unsigned int u = __float_as_uint(f);
    unsigned int r = (u + 0x7fffu + ((u >> 16) & 1u)) >> 16;
    return (unsigned short)r;
}
static __device__ __forceinline__ float bf2f(unsigned short b) {
    return __uint_as_float(((unsigned int)b) << 16);
}
static __device__ __forceinline__ float sigmoidf_(float x) {
    return 1.0f / (1.0f + __expf(-x));
}

// ---------------------------------------------------------------------------
// Kernel 1: permute U_f [512][2048] f32 -> Up bf16 in MFMA B-fragment order.
// Up[(((s*4+g)*16+kt)*64+l)*8+i] = U_f[kt*32+(l>>4)*8+i][g*512+s*16+(l&15)]
// ---------------------------------------------------------------------------
__global__ __launch_bounds__(256)
void uconv_kernel(const float* __restrict__ Uf, unsigned short* __restrict__ Up) {
    int idx = blockIdx.x * 256 + threadIdx.x;   // 0 .. 2^20-1
    int i  = idx & 7;
    int l  = (idx >> 3) & 63;
    int kt = (idx >> 9) & 15;
    int g  = (idx >> 13) & 3;
    int s  = idx >> 15;
    int k  = kt * 32 + ((l >> 4) << 3) + i;
    int col = g * 512 + s * 16 + (l & 15);
    Up[idx] = f2bf(Uf[(size_t)k * G4 + col]);
}

// ---------------------------------------------------------------------------
// Kernel 1b: transpose+convert W_f [512][2048] f32 -> WfT [2048][512] bf16
// ---------------------------------------------------------------------------
__global__ __launch_bounds__(256)
void wtconv_kernel(const float* __restrict__ Wf, unsigned short* __restrict__ WfT) {
    __shared__ float tile[64][65];
    int k0 = blockIdx.x * 64;
    int n0 = blockIdx.y * 64;
    int tid = threadIdx.x;
    int r = tid >> 6, c = tid & 63;
    #pragma unroll
    for (int i = 0; i < 16; ++i)
        tile[r + 4 * i][c] = Wf[(size_t)(k0 + r + 4 * i) * G4 + n0 + c];
    __syncthreads();
    #pragma unroll
    for (int i = 0; i < 16; ++i)
        WfT[(size_t)(n0 + r + 4 * i) * IND + k0 + c] = f2bf(tile[c][r + 4 * i]);
}

// ---------------------------------------------------------------------------
// Kernel 2: lz = sigmoid(field@Wz[:, :512]+bz) * tanh(field@Wz[:, 512:]+bz)
// Output layout: lz[s][b][j] bf16
// ---------------------------------------------------------------------------
__global__ __launch_bounds__(256)
void lz_kernel(const float* __restrict__ field, const float* __restrict__ Wz,
               const float* __restrict__ biasz, unsigned short* __restrict__ lzOut) {
    __shared__ float fs[8][FSD];
    int b = blockIdx.x, s0 = blockIdx.y * 8;
    int tid = threadIdx.x;
    for (int u = tid; u < 8 * FSD; u += 256) {
        int r = u >> 7, k = u & 127;
        fs[r][k] = field[((size_t)b * SEQ + s0 + r) * FSD + k];
    }
    __syncthreads();
    #pragma unroll
    for (int jj = 0; jj < 2; ++jj) {
        int j = tid + jj * 256;
        float accl[8] = {0,0,0,0,0,0,0,0}, accz[8] = {0,0,0,0,0,0,0,0};
        for (int k = 0; k < FSD; ++k) {
            float wl = Wz[(size_t)k * G2 + j];
            float wz = Wz[(size_t)k * G2 + HS + j];
            #pragma unroll
            for (int r = 0; r < 8; ++r) {
                accl[r] += fs[r][k] * wl;
                accz[r] += fs[r][k] * wz;
            }
        }
        float bl = biasz[j], bz = biasz[HS + j];
        #pragma unroll
        for (int r = 0; r < 8; ++r) {
            float l = sigmoidf_(accl[r] + bl);
            float z = tanhf(accz[r] + bz);
            lzOut[(((size_t)(s0 + r)) * BATCH + b) * HS + j] = f2bf(l * z);
        }
    }
}

// ---------------------------------------------------------------------------
// Kernel 3: x_proj MFMA GEMM. A = word (f32, converted on the fly) with
// row = s*128+b; B = WfT bf16 [n][k]. C -> xp bf16 [s][b][4H] (+bias).
// Tile 128x128, BK=64, 4 waves (2x2 of 64x64), XOR-swizzled LDS.
// ---------------------------------------------------------------------------
#define XBM 128
#define XBN 128
#define XBK 64
__global__ __launch_bounds__(256)
void xmm_kernel(const float* __restrict__ word, const unsigned short* __restrict__ WfT,
                const float* __restrict__ bias, unsigned short* __restrict__ xp) {
    __shared__ unsigned short As[XBM * XBK];
    __shared__ unsigned short Bs[XBN * XBK];
    int tid = threadIdx.x;
    int l = tid & 63, w = tid >> 6;
    int wr = w >> 1, wc = w & 1;
    int row0 = blockIdx.x * XBM;
    int col0 = blockIdx.y * XBN;

    f32x4 acc[4][4];
    #pragma unroll
    for (int m = 0; m < 4; ++m)
        #pragma unroll
        for (int n = 0; n < 4; ++n)
            acc[m][n] = (f32x4){0.f, 0.f, 0.f, 0.f};

    for (int k0 = 0; k0 < IND; k0 += XBK) {
        float4 av[4][2];
        short8_t bv[4];
        #pragma unroll
        for (int i = 0; i < 4; ++i) {
            int c = tid + 256 * i;
            int ar = c >> 3, sub = c & 7;
            int grow = row0 + ar;
            int b_ = grow & 127, s_ = grow >> 7;
            const float* ap = word + ((size_t)b_ * SEQ + s_) * IND + k0 + sub * 8;
            av[i][0] = *(const float4*)ap;
            av[i][1] = *(const float4*)(ap + 4);
            bv[i] = *(const short8_t*)(WfT + (size_t)(col0 + ar) * IND + k0 + sub * 8);
        }
        __syncthreads();   // previous iter's compute done with LDS
        #pragma unroll
        for (int i = 0; i < 4; ++i) {
            int c = tid + 256 * i;
            int ar = c >> 3, sub = c & 7;
            int off = ar * 64 + ((sub ^ (ar & 7)) << 3);   // ushort units
            short8_t a8;
            a8[0] = (short)f2bf(av[i][0].x); a8[1] = (short)f2bf(av[i][0].y);
            a8[2] = (short)f2bf(av[i][0].z); a8[3] = (short)f2bf(av[i][0].w);
            a8[4] = (short)f2bf(av[i][1].x); a8[5] = (short)f2bf(av[i][1].y);
            a8[6] = (short)f2bf(av[i][1].z); a8[7] = (short)f2bf(av[i][1].w);
            *(short8_t*)&As[off] = a8;
            *(short8_t*)&Bs[off] = bv[i];
        }
        __syncthreads();
        #pragma unroll
        for (int kt = 0; kt < 2; ++kt) {
            short8_t af[4], bfr[4];
            #pragma unroll
            for (int m = 0; m < 4; ++m) {
                int r = wr * 64 + m * 16 + (l & 15);
                int sub = kt * 4 + (l >> 4);
                af[m] = *(const short8_t*)&As[r * 64 + ((sub ^ (r & 7)) << 3)];
                int cc = wc * 64 + m * 16 + (l & 15);
                bfr[m] = *(const short8_t*)&Bs[cc * 64 + ((sub ^ (cc & 7)) << 3)];
            }
            #pragma unroll
            for (int m = 0; m < 4; ++m)
                #pragma unroll
                for (int n = 0; n < 4; ++n)
                    acc[m][n] = __builtin_amdgcn_mfma_f32_16x16x32_bf16(
                        af[m], bfr[n], acc[m][n], 0, 0, 0);
        }
    }
    #pragma unroll
    for (int m = 0; m < 4; ++m) {
        int grow = row0 + wr * 64 + m * 16 + (l >> 4) * 4;
        #pragma unroll
        for (int n = 0; n < 4; ++n) {
            int gcol = col0 + wc * 64 + n * 16 + (l & 15);
            float bsv = bias[gcol];
            #pragma unroll
            for (int r = 0; r < 4; ++r)
                xp[(size_t)(grow + r) * G4 + gcol] = f2bf(acc[m][n][r] + bsv);
        }
    }
}

// ---------------------------------------------------------------------------
// Kernel 4: recurrence. rec3 partitioning (256 blocks, 1 slice/block) +
// LDS-resident U fragments (loaded once, ds_read_b128 per step) +
// rec5's proven flag-per-block protocol (2-slot rotating flags, 2KB).
// ---------------------------------------------------------------------------
__global__ __launch_bounds__(256, 1)
void rec7_kernel(const unsigned short* __restrict__ xp,
                 const unsigned short* __restrict__ lz,
                 const unsigned short* __restrict__ Up,
                 float* __restrict__ out,
                 unsigned short* __restrict__ hbuf,
                 unsigned int* __restrict__ flags) {
    const size_t HSEQ = (size_t)BATCH * SEQ * HS;
    const int HBG = GB * HS;   // 8192 ushorts per (slot, group)

    int bid = blockIdx.x;
    int g = bid & 7;
    int s = bid >> 3;          // 0..31
    int tid = threadIdx.x;
    int w = tid >> 6;          // gate
    int l = tid & 63;

    // U fragments staged once into LDS: [gate][kt][lane] 16B each = 64KB.
    __shared__ short8_t Ubs[4][16][64];
    {
        const short8_t* upw = (const short8_t*)(Up + ((size_t)(s * 4 + w) * 16) * 512);
        #pragma unroll
        for (int kt = 0; kt < 16; ++kt)
            Ubs[w][kt][l] = upw[kt * 64 + l];
    }
    __shared__ float gbuf[4][16][18];   // <=2-way (free) bank pattern
    __syncthreads();

    int eb = tid >> 4;            // batch-local 0..15
    int ej = tid & 15;            // col-local 0..15
    int jg = s * SJ + ej;         // global hidden col
    int bg = g * GB + eb;         // global batch
    // hbuf ushort index for h[b][j] in A-fragment order
    int widx = (((jg >> 5) * 64 + eb + (((jg >> 3) & 3) << 4)) << 3) + (jg & 7);

    // 2-slot rotating flags: flags[g][slot][s], value = t+1 at step t.
    unsigned int* fl = flags + (size_t)g * 2 * NS;

    float c = 0.f, h_last = 0.f;

    for (int t = 0; t < SEQ; ++t) {
        // prefetch gate inputs (independent of h) — overlap with poll
        size_t xb = ((size_t)t * BATCH + bg) * G4;
        float pgi = bf2f(xp[xb + jg]);
        float pgf = bf2f(xp[xb + HS + jg]);
        float pgg = bf2f(xp[xb + 2 * HS + jg]);
        float pgo = bf2f(xp[xb + 3 * HS + jg]);
        float plz = bf2f(lz[((size_t)t * BATCH + bg) * HS + jg]);

        f32x4 acc0 = {0.f, 0.f, 0.f, 0.f};
        f32x4 acc1 = {0.f, 0.f, 0.f, 0.f};
        if (t > 0) {
            // all-wave poll of the 32 producer flags of step t-1
            const unsigned int* fp = fl + ((t - 1) & 1) * NS + (l & 31);
            int spins = 0;
            unsigned v;
            do {
                v = __hip_atomic_load(fp, __ATOMIC_RELAXED,
                                      __HIP_MEMORY_SCOPE_AGENT);
                if (++spins > (1 << 20)) break;
            } while (!__all(v == (unsigned)t));

            // A-fragment loads (coherent u64 pairs, proven form) + LDS B reads
            const unsigned long long* ha64 = (const unsigned long long*)
                (hbuf + (size_t)(((t - 1) & 1) * NG + g) * HBG);
            #pragma unroll
            for (int kt = 0; kt < 16; ++kt) {
                union { unsigned long long u[2]; short8_t v8; } A;
                int i0 = (kt * 64 + l) * 2;
                A.u[0] = __hip_atomic_load(&ha64[i0], __ATOMIC_RELAXED,
                                           __HIP_MEMORY_SCOPE_AGENT);
                A.u[1] = __hip_atomic_load(&ha64[i0 + 1], __ATOMIC_RELAXED,
                                           __HIP_MEMORY_SCOPE_AGENT);
                short8_t bf = Ubs[w][kt][l];
                if (kt & 1)
                    acc1 = __builtin_amdgcn_mfma_f32_16x16x32_bf16(A.v8, bf, acc1, 0, 0, 0);
                else
                    acc0 = __builtin_amdgcn_mfma_f32_16x16x32_bf16(A.v8, bf, acc0, 0, 0, 0);
            }
            acc0 += acc1;
        }
        // stash gate tile: D layout col=lane&15, row=(lane>>4)*4+reg
        #pragma unroll
        for (int r = 0; r < 4; ++r)
            gbuf[w][(l >> 4) * 4 + r][l & 15] = acc0[r];
        __syncthreads();

        // epilogue: thread (eb, ej)
        float gi = gbuf[0][eb][ej] + pgi;
        float gf = gbuf[1][eb][ej] + pgf;
        float gg = gbuf[2][eb][ej] + pgg;
        float go = gbuf[3][eb][ej] + pgo;
        float i_ = sigmoidf_(gi);
        float f_ = sigmoidf_(gf + 1.0f);
        float g_ = tanhf(gg);
        float o_ = sigmoidf_(go);
        c = f_ * c + i_ * g_ + plz;
        float h = o_ * tanhf(c);
        h_last = h;

        // h exchange first (critical path): pack u32 pairs, coherent store
        unsigned short hv = f2bf(h);
        unsigned partner = (unsigned)(unsigned short)__shfl_down((int)hv, 1);
        if ((ej & 1) == 0) {
            unsigned int* hb32 = (unsigned int*)
                (hbuf + (size_t)((t & 1) * NG + g) * HBG);
            __hip_atomic_store(&hb32[widx >> 1], (unsigned)hv | (partner << 16),
                               __ATOMIC_RELAXED, __HIP_MEMORY_SCOPE_AGENT);
        }
        asm volatile("s_waitcnt vmcnt(0)" ::: "memory");
        __syncthreads();   // all threads' h stores drained; gbuf reads done
        if (tid == 0)
            __hip_atomic_store(&fl[(t & 1) * NS + s], (unsigned)(t + 1),
                               __ATOMIC_RELAXED, __HIP_MEMORY_SCOPE_AGENT);

        // hidden-seq output AFTER flag publication (off the critical path)
        out[((size_t)bg * SEQ + t) * HS + jg] = h;
    }

    // finals: h_T then c_T
    out[HSEQ + (size_t)bg * HS + jg] = h_last;
    out[HSEQ + (size_t)BATCH * HS + (size_t)bg * HS + jg] = c;
}

// ---------------------------------------------------------------------------
extern "C" void kernel_launch(void* const* d_in, const int* in_sizes, int n_in,
                              void* d_out, int out_size, void* d_ws, size_t ws_size,
                              hipStream_t stream) {
    const float* word   = (const float*)d_in[0];
    const float* field  = (const float*)d_in[1];
    const float* Wf     = (const float*)d_in[2];
    const float* Wz     = (const float*)d_in[3];
    const float* Uf     = (const float*)d_in[4];
    const float* bias_f = (const float*)d_in[5];
    const float* biasz  = (const float*)d_in[6];
    float* out = (float*)d_out;

    // Workspace (total ~340.0 MB, below round-4 proven usage):
    //   xp   : bf16 [S][B][4H] = 268,435,456
    //   lz   : bf16 [S][B][H]  =  67,108,864
    //   Up   : bf16 frag-order =   2,097,152
    //   WfT  : bf16 [N][K]     =   2,097,152
    //   hbuf : bf16 2x8x8192   =     262,144
    //   flags: u32 8x2x32      =       2,048
    char* p = (char*)d_ws;
    unsigned short* xp   = (unsigned short*)p;  p += (size_t)SEQ * BATCH * G4 * 2;
    unsigned short* lzb  = (unsigned short*)p;  p += (size_t)SEQ * BATCH * HS * 2;
    unsigned short* Up   = (unsigned short*)p;  p += (size_t)IND * G4 * 2;
    unsigned short* WfT  = (unsigned short*)p;  p += (size_t)G4 * IND * 2;
    unsigned short* hbuf = (unsigned short*)p;  p += (size_t)2 * NG * GB * HS * 2;
    unsigned int*   flags= (unsigned int*)p;    p += (size_t)NG * 2 * NS * 4;

    // clear flags (harness does NOT re-poison ws between graph replays)
    hipMemsetAsync(flags, 0, (size_t)NG * 2 * NS * 4, stream);

    uconv_kernel<<<(IND * G4) / 256, 256, 0, stream>>>(Uf, Up);

    dim3 gt(IND / 64, G4 / 64);
    wtconv_kernel<<<gt, 256, 0, stream>>>(Wf, WfT);

    dim3 gl(BATCH, SEQ / 8);
    lz_kernel<<<gl, 256, 0, stream>>>(field, Wz, biasz, lzb);

    dim3 gx((SEQ * BATCH) / XBM, G4 / XBN);
    xmm_kernel<<<gx, 256, 0, stream>>>(word, WfT, bias_f, xp);

    rec7_kernel<<<NG * NS, 256, 0, stream>>>(xp, lzb, Up, out, hbuf, flags);
}